// Round 6
// baseline (344.043 us; speedup 1.0000x reference)
//
#include <hip/hip_runtime.h>

#define T_FRAMES 32768
#define ROWF 1629           // 543*3 floats per frame
#define FACEF 1404          // face region floats [0,1404): lips live here
#define NSEG 512
#define NVAL 122            // 42 hand + 80 lips values per frame
#define STRIDE 128          // stage row stride (floats)
#define K1_BLOCKS 512       // 512 blocks x 8 waves x 8 frames = 32768

// -------------------------------------------------------------------------
// K1: wave-private LDS staging. Each wave streams its frame's face region
// (5616 B, 22 coalesced dword loads; row base only 4B-aligned so no float4)
// into a private LDS slice, then gathers the 80 lip values from LDS.
// No intra-loop barrier: per-wave DS ops are in-order, so the 16 resident
// waves' copy/gather phases interleave freely. Hand values (10 dense lines)
// stay direct gathers. Converts the 40-scattered-line/frame HBM gather
// (measured ~90us, latency-bound) into a ~203MB coalesced stream (~35us).
// -------------------------------------------------------------------------
__global__ __launch_bounds__(512) void k1_face(
    const float* __restrict__ frames, const int* __restrict__ lips_idx,
    int* __restrict__ keep, float* __restrict__ psum, int* __restrict__ pcnt,
    float* __restrict__ stage) {
  __shared__ float face[8][FACEF + 4];        // 8 x 5632 B = 45056 B
  __shared__ float ls[80];
  __shared__ int lc[80];
  __shared__ int idx3[40];
  int tid = threadIdx.x;
  if (tid < 80) { ls[tid] = 0.0f; lc[tid] = 0; }
  if (tid < 40) idx3[tid] = lips_idx[tid] * 3;
  __syncthreads();                            // idx3/ls/lc visible to all

  int lane = tid & 63;
  int wv = tid >> 6;                          // 0..7
  float* fb = face[wv];

  // per-lane constant offsets
  int jh = lane >> 1, ch = lane & 1;
  int offL = 1404 + 3 * jh + ch;              // (468+j)*3+c
  int offR = 1566 + 3 * jh + ch;              // (522+j)*3+c
  int offA = idx3[lane >> 1] + (lane & 1);                         // v = lane
  int offB = (lane < 16) ? (idx3[(lane + 64) >> 1] + (lane & 1)) : 0; // v=64+lane

  int base_t = (blockIdx.x * 8 + wv) * 8;     // 8 consecutive frames per wave
  for (int ff = 0; ff < 8; ++ff) {
    int t = base_t + ff;
    const float* f = frames + (size_t)t * ROWF;

    // hand gathers (independent; issue alongside the stream)
    float lh = 0.0f, rh = 1.0f;
    if (lane < 42) { lh = f[offL]; rh = f[offR]; }

    // face stream -> private LDS slice (22 coalesced 256B loads)
    for (int p = lane; p < FACEF; p += 64) fb[p] = f[p];

    // keep flag from hand values (summands >= 0: sum!=0 <=> any!=0)
    float hv = 0.0f;
    if (lane < 42) {
      float a = ch ? (1.0f - lh) : lh;        // lh: [x, 1-y]
      float b = 1.0f - rh;                    // rh: [1-x, 1-y]
      a = (a == a) ? a : 0.0f;                // nan_to_num
      b = (b == b) ? b : 0.0f;
      hv = a + b;
    }
    int kp = (__ballot(hv != 0.0f) != 0ull) ? 1 : 0;
    if (lane == 0) keep[t] = kp;

    if (kp) {                                 // wave-uniform
      float* srow = stage + (size_t)t * STRIDE;
      if (lane < 42) srow[lane] = hv;
      float x = fb[offA];                     // LDS gather (in-order vs writes)
      srow[42 + lane] = x;                    // NaN preserved for K3
      if (x == x) { atomicAdd(&ls[lane], x); atomicAdd(&lc[lane], 1); }
      if (lane < 16) {
        float y = fb[offB];
        srow[106 + lane] = y;
        if (y == y) { atomicAdd(&ls[64 + lane], y); atomicAdd(&lc[64 + lane], 1); }
      }
    }
  }

  __syncthreads();
  if (tid < 80) {                             // [block][80]: coalesced
    psum[blockIdx.x * 80 + tid] = ls[tid];
    pcnt[blockIdx.x * 80 + tid] = lc[tid];
  }
}

// -------------------------------------------------------------------------
// K2: (a) reduce 512 per-block lip partials; (b) prefix scan keep[] ->
// kept_t[], total S.
// -------------------------------------------------------------------------
__global__ __launch_bounds__(1024) void k2_scan(
    const int* __restrict__ keep, int* __restrict__ kept_t,
    int* __restrict__ Sp, const float* __restrict__ psum,
    const int* __restrict__ pcnt, float* __restrict__ lip_sum,
    int* __restrict__ lip_cnt) {
  __shared__ int wsum[16];
  int tid = threadIdx.x;
  int lane = tid & 63, wv = tid >> 6;

  // ---- (a) lip partial reduction ----
  if (tid < 80) {
    float s = 0.0f; int c = 0;
    for (int b = 0; b < K1_BLOCKS; ++b) {
      s += psum[b * 80 + tid];
      c += pcnt[b * 80 + tid];
    }
    lip_sum[tid] = s; lip_cnt[tid] = c;
  }

  // ---- (b) scan ----
  const int PER = T_FRAMES / 1024;            // 32
  int base = tid * PER;
  int fl[PER];
  int local = 0;
  #pragma unroll
  for (int k = 0; k < PER; ++k) { fl[k] = keep[base + k]; local += fl[k]; }

  int scan = local;
  #pragma unroll
  for (int off = 1; off < 64; off <<= 1) {
    int n = __shfl_up(scan, off);
    if (lane >= off) scan += n;
  }
  if (lane == 63) wsum[wv] = scan;
  __syncthreads();
  if (tid < 16) {
    int v = wsum[tid];
    #pragma unroll
    for (int off = 1; off < 16; off <<= 1) {
      int n = __shfl_up(v, off);
      if (tid >= off) v += n;
    }
    wsum[tid] = v;
  }
  __syncthreads();
  int excl = ((wv == 0) ? 0 : wsum[wv - 1]) + (scan - local);
  #pragma unroll
  for (int k = 0; k < PER; ++k) {
    if (fl[k]) kept_t[excl++] = base + k;
  }
  if (tid == 1023) Sp[0] = wsum[15];
}

// -------------------------------------------------------------------------
// K3: one block per segment; 512 threads = 4-way row split x 128 values.
// b[i] = (i*(S-1))>>9 (exact vs np.linspace->int32); rank S-1 (seg 512)
// dropped, matching JAX segment_sum OOB-drop. Stage rows read coalesced.
// -------------------------------------------------------------------------
__global__ __launch_bounds__(512) void k3_segments(
    const float* __restrict__ stage, const int* __restrict__ kept_t,
    const int* __restrict__ Sp, const float* __restrict__ lip_sum,
    const int* __restrict__ lip_cnt, float* __restrict__ out, int out_size) {
  __shared__ int seglist[128];
  __shared__ float part[4][128];
  int tid = threadIdx.x;
  int v = tid & 127;                          // value index (122 used)
  int r = tid >> 7;                           // 0..3
  int seg = blockIdx.x;
  long long Sm1 = (long long)Sp[0] - 1;
  if (Sm1 < 0) Sm1 = 0;
  int lo = (int)(((long long)seg * Sm1) >> 9);
  int hi = (int)(((long long)(seg + 1) * Sm1) >> 9);
  int cnt = hi - lo;

  for (int k = tid; k < cnt; k += 512) seglist[k] = kept_t[lo + k];
  __syncthreads();

  float cm = 0.0f;                            // column mean (lips only)
  if (v >= 42 && v < NVAL) {
    int w = v - 42;
    int c = lip_cnt[w];
    cm = (c == 0) ? 0.0f : lip_sum[w] / (float)c;
  }

  float acc = 0.0f;
  if (v < NVAL) {
    for (int k = r; k < cnt; k += 4) {
      float x = stage[(size_t)seglist[k] * STRIDE + v];
      acc += (x == x) ? x : cm;               // hand values never NaN
    }
  }
  part[r][v] = acc;
  __syncthreads();
  if (r == 0 && v < NVAL) {
    float tot = part[0][v] + part[1][v] + part[2][v] + part[3][v];
    float mean = (cnt == 0) ? 0.0f : tot / (float)cnt;
    int o = seg * NVAL + v;
    if (o < out_size) out[o] = mean;
  }
}

// -------------------------------------------------------------------------
extern "C" void kernel_launch(void* const* d_in, const int* in_sizes, int n_in,
                              void* d_out, int out_size, void* d_ws, size_t ws_size,
                              hipStream_t stream) {
  const float* frames = (const float*)d_in[0];
  const int* lips_idx = (const int*)d_in[1];
  float* out = (float*)d_out;

  char* ws = (char*)d_ws;
  int* keep      = (int*)(ws);                     // 131072 B
  int* kept_t    = (int*)(ws + 131072);            // 131072 B
  int* Sp        = (int*)(ws + 262144);            // 64 B
  float* lip_sum = (float*)(ws + 262208);          // 512 B
  int* lip_cnt   = (int*)(ws + 262720);            // 512 B
  float* psum    = (float*)(ws + 263232);          // 512*80*4 = 163840 B
  int* pcnt      = (int*)(ws + 427072);            // 163840 B
  float* stage   = (float*)(ws + 590912);          // 32768*128*4 = 16 MiB

  // no zero-init needed: every word read is written first (no global atomics)

  k1_face<<<K1_BLOCKS, 512, 0, stream>>>(frames, lips_idx, keep, psum,
                                         pcnt, stage);
  k2_scan<<<1, 1024, 0, stream>>>(keep, kept_t, Sp, psum, pcnt, lip_sum,
                                  lip_cnt);
  k3_segments<<<NSEG, 512, 0, stream>>>(stage, kept_t, Sp, lip_sum, lip_cnt,
                                        out, out_size);
}